// Round 3
// baseline (11.221 us; speedup 1.0000x reference)
//
#include <hip/hip_runtime.h>

#define CANVAS 28
#define TSTEPS 64
#define GCONST 196.0f   // (SIZE/2)^2

// out[b,i,j] = min(1, exp(P(i,j) + max_t [A_t + cx_t*rj + cy_t*ri]))
// A = ln(I) - g(x^2+y^2), cx = 2gx, cy = 2gy, P = -g(rj^2 + ri^2)
//
// No LDS: lane t holds stroke t's coeffs in VGPRs; v_readlane (VALU pipe,
// immediate lane index via full unroll) broadcasts them to SGPRs per step.
__global__ __launch_bounds__(128) void draw_image_kernel(
    const float* __restrict__ x,   // (B, 64, 3)
    float* __restrict__ out)       // (B, 28, 28)
{
    const int b    = blockIdx.x;
    const int tid  = threadIdx.x;   // 0..127
    const int wave = tid >> 6;      // 0,1: rows 14*wave .. 14*wave+13
    const int lane = tid & 63;

    // --- per-lane stroke coefficients (lane t owns stroke t) ---
    const float xv = x[b * 192 + lane * 3 + 0];
    const float yv = x[b * 192 + lane * 3 + 1];
    const float iv = x[b * 192 + lane * 3 + 2];
    const float vA  = __logf(iv) - GCONST * (xv * xv + yv * yv);  // -inf ok for iv=0
    const float vCx = 2.0f * GCONST * xv;
    const float vCy = 2.0f * GCONST * yv;

    // --- pixel ownership: lane (<56) -> row = 14*wave + lane/4, cols 7*(lane%4).. ---
    const int lrow = lane >> 2;
    const int lcg  = lane & 3;
    const bool active = (lrow < 14);
    const int row = 14 * wave + (active ? lrow : 0);
    const float ri = (float)row * (1.0f / CANVAS) - 0.5f;

    float rj[7];
    #pragma unroll
    for (int k = 0; k < 7; ++k)
        rj[k] = (float)(lcg * 7 + k) * (1.0f / CANVAS) - 0.5f;

    float m[7];
    #pragma unroll
    for (int k = 0; k < 7; ++k) m[k] = -1e30f;

    #pragma unroll
    for (int t = 0; t < TSTEPS; ++t) {
        const float A  = __builtin_bit_cast(float,
            __builtin_amdgcn_readlane(__builtin_bit_cast(int, vA),  t));
        const float cx = __builtin_bit_cast(float,
            __builtin_amdgcn_readlane(__builtin_bit_cast(int, vCx), t));
        const float cy = __builtin_bit_cast(float,
            __builtin_amdgcn_readlane(__builtin_bit_cast(int, vCy), t));
        const float h = __builtin_fmaf(cy, ri, A);
        #pragma unroll
        for (int k = 0; k < 7; ++k)
            m[k] = fmaxf(m[k], __builtin_fmaf(cx, rj[k], h));
    }

    if (active) {
        const float pc = -GCONST * ri * ri;
        float* outp = out + b * (CANVAS * CANVAS) + row * CANVAS + lcg * 7;
        #pragma unroll
        for (int k = 0; k < 7; ++k) {
            const float p = __builtin_fmaf(-GCONST, rj[k] * rj[k], pc);
            outp[k] = fminf(__expf(m[k] + p), 1.0f);
        }
    }
}

extern "C" void kernel_launch(void* const* d_in, const int* in_sizes, int n_in,
                              void* d_out, int out_size, void* d_ws, size_t ws_size,
                              hipStream_t stream) {
    const float* x = (const float*)d_in[0];
    float* out = (float*)d_out;
    const int B = in_sizes[0] / (TSTEPS * 3);   // 1024
    draw_image_kernel<<<dim3(B), dim3(128), 0, stream>>>(x, out);
}